// Round 5
// baseline (225.296 us; speedup 1.0000x reference)
//
#include <hip/hip_runtime.h>
#include <math.h>

// Problem constants
#define N_IMG 16
#define C_CH 3
#define H_DIM 512
#define W_DIM 512
#define HW (H_DIM * W_DIM)              // 262144
#define KS 7
#define PAD 3

// Tiling: 64 wide x 32 tall output tile, 3-halo each side.
#define TSX 64
#define TSY 32
#define TILE_H (TSY + 2 * PAD)          // 38
#define TSTRIDE 72                      // LDS row stride (floats); interior cols [4..67], halo [1..3],[68..70]
#define TPB 256
#define TILES_PER_IMG 128               // (512/64)*(512/32)
#define NBLOCKS (N_IMG * TILES_PER_IMG) // 2048

__device__ __forceinline__ int reflect_i(int g, int n) {
    // jnp 'reflect' (no edge duplication)
    return (g < 0) ? -g : ((g >= n) ? (2 * n - 2 - g) : g);
}

// ---------------------------------------------------------------------------
// Single fused kernel:
//  (a) issue ALL global loads up front into registers (deep MLP: ~18 float4
//      + 6 scalars outstanding per lane) — fixes the latency bound seen at
//      VGPR=28 (only ~2 loads in flight -> 2.5 TB/s),
//  (b) residual tile -> LDS, 7x7 local unbiased variance via ring row-sums
//      (8 px/thread), per-block partials {sum r, sum r^2, sum var*r} -> ws,
//  (c) last block (threadfence + atomic counter) reduces partials, applies
//      patch_w = pvar^0.2, writes the scalar. No separate finalize kernel.
// ---------------------------------------------------------------------------
__global__ __launch_bounds__(TPB) void k_fused(const float* __restrict__ pred,
                                               const float* __restrict__ targ,
                                               float* __restrict__ pr,
                                               float* __restrict__ pr2,
                                               float* __restrict__ pc,
                                               unsigned int* __restrict__ counter,
                                               float* __restrict__ out) {
    __shared__ __align__(16) float tile[TILE_H * TSTRIDE];

    const int bid = blockIdx.x;
    const int n   = bid >> 7;              // 128 tiles per image
    const int t   = bid & 127;
    const int by  = t >> 3;                // 0..15
    const int bx  = t & 7;                 // 0..7
    const int tid = threadIdx.x;
    const int y0  = by * TSY - PAD;

    const float*  pb = pred + (size_t)n * C_CH * HW;
    const float*  qb = targ + (size_t)n * C_CH * HW;
    const float4* P  = (const float4*)pb;
    const float4* Q  = (const float4*)qb;
    const int PL4 = HW / 4;                // plane stride in float4

    // ---- phase 1: issue all global loads into registers (no consumption) ----
    // interior: 38 rows x 16 float4 = 608 slots = 2*256 + 96
    float4 pv[3][3], qv[3][3];
    int irow[3], ic4[3];
    const bool act2 = (tid < 96);
#pragma unroll
    for (int it = 0; it < 3; ++it) {
        const int s   = tid + it * TPB;
        const int row = s >> 4;
        const int c4  = s & 15;
        irow[it] = row; ic4[it] = c4;
        if (it < 2 || act2) {
            const int gy  = reflect_i(y0 + row, H_DIM);
            const int off = gy * (W_DIM / 4) + bx * 16 + c4;
            pv[it][0] = P[off]; pv[it][1] = P[off + PL4]; pv[it][2] = P[off + 2 * PL4];
            qv[it][0] = Q[off]; qv[it][1] = Q[off + PL4]; qv[it][2] = Q[off + 2 * PL4];
        }
    }
    // halo: 38 rows x (3 left + 3 right) = 228 slots
    const bool hact = (tid < TILE_H * 6);
    float hp0 = 0.f, hp1 = 0.f, hp2 = 0.f, hq0 = 0.f, hq1 = 0.f, hq2 = 0.f;
    int hrow = 0, hlx = 0;
    if (hact) {
        hrow = tid / 6;
        const int k = tid - hrow * 6;
        hlx = (k < 3) ? (1 + k) : (65 + k);                // 1..3 or 68..70
        const int gx  = reflect_i(bx * TSX + hlx - 4, W_DIM);
        const int gy  = reflect_i(y0 + hrow, H_DIM);
        const int off = gy * W_DIM + gx;
        hp0 = pb[off]; hp1 = pb[off + HW]; hp2 = pb[off + 2 * HW];
        hq0 = qb[off]; hq1 = qb[off + HW]; hq2 = qb[off + 2 * HW];
    }

    // ---- phase 2: consume -> residual -> LDS ----
#pragma unroll
    for (int it = 0; it < 3; ++it) {
        if (it < 2 || act2) {
            float4 r;
            r.x = fabsf(qv[it][0].x - pv[it][0].x) + fabsf(qv[it][1].x - pv[it][1].x) + fabsf(qv[it][2].x - pv[it][2].x);
            r.y = fabsf(qv[it][0].y - pv[it][0].y) + fabsf(qv[it][1].y - pv[it][1].y) + fabsf(qv[it][2].y - pv[it][2].y);
            r.z = fabsf(qv[it][0].z - pv[it][0].z) + fabsf(qv[it][1].z - pv[it][1].z) + fabsf(qv[it][2].z - pv[it][2].z);
            r.w = fabsf(qv[it][0].w - pv[it][0].w) + fabsf(qv[it][1].w - pv[it][1].w) + fabsf(qv[it][2].w - pv[it][2].w);
            *(float4*)&tile[irow[it] * TSTRIDE + 4 + ic4[it] * 4] = r;   // 16B-aligned
        }
    }
    if (hact)
        tile[hrow * TSTRIDE + hlx] = fabsf(hq0 - hp0) + fabsf(hq1 - hp1) + fabsf(hq2 - hp2);
    __syncthreads();

    // ---- phase 3: 8 vertically-adjacent outputs per thread (ring row sums) ----
    const int tx = tid & 63;               // output column 0..63
    const int r0 = (tid >> 6) << 3;        // output rows r0..r0+7

    float rS[KS], rSS[KS];
    float S = 0.f, SS = 0.f;
#pragma unroll
    for (int d = 0; d < KS; ++d) {
        const float* rw = &tile[(r0 + d) * TSTRIDE + 1 + tx];
        float s = 0.f, ss = 0.f;
#pragma unroll
        for (int j = 0; j < KS; ++j) { const float v = rw[j]; s += v; ss += v * v; }
        rS[d] = s; rSS[d] = ss; S += s; SS += ss;
    }

    float acc_r = 0.f, acc_r2 = 0.f, acc_c = 0.f;
#pragma unroll
    for (int k = 0; k < 8; ++k) {
        if (k > 0) {
            const float* rw = &tile[(r0 + 6 + k) * TSTRIDE + 1 + tx];
            float s = 0.f, ss = 0.f;
#pragma unroll
            for (int j = 0; j < KS; ++j) { const float v = rw[j]; s += v; ss += v * v; }
            S  += s  - rS[k - 1];          // exactly 7 slides: slots 0..6, no reuse
            SS += ss - rSS[k - 1];
        }
        const float pix_var = (SS - S * S * (1.0f / 49.0f)) * (1.0f / 48.0f);
        const float center  = tile[(r0 + k + 3) * TSTRIDE + 4 + tx];
        acc_r  += center;
        acc_r2 += center * center;
        acc_c  += pix_var * center;
    }

    // ---- phase 4: block reduce 3 floats, write partials ----
#pragma unroll
    for (int off = 32; off > 0; off >>= 1) {
        acc_r  += __shfl_down(acc_r,  off);
        acc_r2 += __shfl_down(acc_r2, off);
        acc_c  += __shfl_down(acc_c,  off);
    }
    __shared__ float sh_r[4], sh_r2[4], sh_c[4];
    __shared__ int lastflag;
    const int lane = tid & 63;
    const int wave = tid >> 6;
    if (lane == 0) { sh_r[wave] = acc_r; sh_r2[wave] = acc_r2; sh_c[wave] = acc_c; }
    __syncthreads();
    if (tid == 0) {
        pr [bid] = sh_r [0] + sh_r [1] + sh_r [2] + sh_r [3];
        pr2[bid] = sh_r2[0] + sh_r2[1] + sh_r2[2] + sh_r2[3];
        pc [bid] = sh_c [0] + sh_c [1] + sh_c [2] + sh_c [3];
        __threadfence();                              // release partials
        const unsigned prev = atomicAdd(counter, 1u); // device-scope
        lastflag = (prev == NBLOCKS - 1);
    }
    __syncthreads();

    // ---- phase 5: last block reduces all partials and writes the scalar ----
    if (lastflag) {
        __threadfence();                              // acquire
        double local = 0.0;                           // wave w handles images 4w..4w+3
#pragma unroll
        for (int im4 = 0; im4 < 4; ++im4) {
            const int im = wave * 4 + im4;
            double R = 0.0, R2 = 0.0, Cs = 0.0;
            for (int i = lane; i < TILES_PER_IMG; i += 64) {
                const int idx = im * TILES_PER_IMG + i;
                R  += (double)pr[idx];
                R2 += (double)pr2[idx];
                Cs += (double)pc[idx];
            }
#pragma unroll
            for (int off = 32; off > 0; off >>= 1) {
                R  += __shfl_down(R,  off);
                R2 += __shfl_down(R2, off);
                Cs += __shfl_down(Cs, off);
            }
            if (lane == 0) {
                const double pvar = (R2 - R * R / (double)HW) / (double)(HW - 1);
                local += pow(pvar, 0.2) * Cs;
            }
        }
        __shared__ double shd[4];
        if (lane == 0) shd[wave] = local;
        __syncthreads();                              // uniform branch: safe
        if (tid == 0)
            out[0] = (float)((shd[0] + shd[1] + shd[2] + shd[3])
                             / ((double)N_IMG * C_CH * HW));
    }
}

extern "C" void kernel_launch(void* const* d_in, const int* in_sizes, int n_in,
                              void* d_out, int out_size, void* d_ws, size_t ws_size,
                              hipStream_t stream) {
    const float* pred = (const float*)d_in[0];
    const float* targ = (const float*)d_in[1];

    float*    pr      = (float*)d_ws;
    float*    pr2     = pr  + NBLOCKS;
    float*    pc      = pr2 + NBLOCKS;
    unsigned* counter = (unsigned*)(pc + NBLOCKS);
    float*    out     = (float*)d_out;

    hipMemsetAsync(counter, 0, sizeof(unsigned), stream);   // ws is re-poisoned 0xAA
    k_fused<<<NBLOCKS, TPB, 0, stream>>>(pred, targ, pr, pr2, pc, counter, out);
}

// Round 6
// 130.159 us; speedup vs baseline: 1.7309x; 1.7309x over previous
//
#include <hip/hip_runtime.h>
#include <math.h>

// Problem constants
#define N_IMG 16
#define C_CH 3
#define H_DIM 512
#define W_DIM 512
#define HW (H_DIM * W_DIM)              // 262144
#define HW4 (HW / 4)                    // 65536 float4 per plane
#define KS 7
#define PAD 3

// Kernel A: 2048 blocks, 256 threads, 2 float4/thread (512 float4/block)
#define ABLOCKS 2048
#define A_PER_IMG (ABLOCKS / N_IMG)     // 128 blocks/image

// Kernel B tiling: 64 wide x 32 tall output tile, 3-halo each side.
#define TSX 64
#define TSY 32
#define TILE_H (TSY + 2 * PAD)          // 38
#define TSTRIDE 72                      // LDS row stride; interior cols [4..67], halo [1..3],[68..70]
#define TPB 256
#define TILES_PER_IMG 128               // (512/64)*(512/32)
#define BBLOCKS (N_IMG * TILES_PER_IMG) // 2048

__device__ __forceinline__ int reflect_i(int g, int n) {
    // jnp 'reflect' (no edge duplication)
    return (g < 0) ? -g : ((g >= n) ? (2 * n - 2 - g) : g);
}

// ---------------------------------------------------------------------------
// Kernel A: pure streaming. residual = sum_c |t-p| -> ws (float4), plus
// per-block {sum r, sum r^2} partials. No barriers between load and use,
// 12 independent float4 loads per thread -> memcpy-like BW.
// ---------------------------------------------------------------------------
__global__ __launch_bounds__(TPB) void k_resid(const float4* __restrict__ pred,
                                               const float4* __restrict__ targ,
                                               float4* __restrict__ resid,
                                               float* __restrict__ pr,
                                               float* __restrict__ pr2) {
    const int bid = blockIdx.x;
    const int tid = threadIdx.x;
    const int n   = bid >> 7;                        // 128 blocks per image
    const int o0  = (bid & 127) * 512 + tid;         // float4 index within image
    const int b4  = n * C_CH * HW4;                  // image base (float4)

    // 12 independent loads (compiler interleaves; all independent of each other)
    const float4 pa0 = pred[b4 + o0];
    const float4 pb0 = pred[b4 + HW4 + o0];
    const float4 pc0 = pred[b4 + 2 * HW4 + o0];
    const float4 qa0 = targ[b4 + o0];
    const float4 qb0 = targ[b4 + HW4 + o0];
    const float4 qc0 = targ[b4 + 2 * HW4 + o0];
    const int o1 = o0 + 256;
    const float4 pa1 = pred[b4 + o1];
    const float4 pb1 = pred[b4 + HW4 + o1];
    const float4 pc1 = pred[b4 + 2 * HW4 + o1];
    const float4 qa1 = targ[b4 + o1];
    const float4 qb1 = targ[b4 + HW4 + o1];
    const float4 qc1 = targ[b4 + 2 * HW4 + o1];

    float4 r0, r1;
    r0.x = fabsf(qa0.x - pa0.x) + fabsf(qb0.x - pb0.x) + fabsf(qc0.x - pc0.x);
    r0.y = fabsf(qa0.y - pa0.y) + fabsf(qb0.y - pb0.y) + fabsf(qc0.y - pc0.y);
    r0.z = fabsf(qa0.z - pa0.z) + fabsf(qb0.z - pb0.z) + fabsf(qc0.z - pc0.z);
    r0.w = fabsf(qa0.w - pa0.w) + fabsf(qb0.w - pb0.w) + fabsf(qc0.w - pc0.w);
    r1.x = fabsf(qa1.x - pa1.x) + fabsf(qb1.x - pb1.x) + fabsf(qc1.x - pc1.x);
    r1.y = fabsf(qa1.y - pa1.y) + fabsf(qb1.y - pb1.y) + fabsf(qc1.y - pc1.y);
    r1.z = fabsf(qa1.z - pa1.z) + fabsf(qb1.z - pb1.z) + fabsf(qc1.z - pc1.z);
    r1.w = fabsf(qa1.w - pa1.w) + fabsf(qb1.w - pb1.w) + fabsf(qc1.w - pc1.w);

    resid[n * HW4 + o0] = r0;
    resid[n * HW4 + o1] = r1;

    float s  = r0.x + r0.y + r0.z + r0.w + r1.x + r1.y + r1.z + r1.w;
    float ss = r0.x * r0.x + r0.y * r0.y + r0.z * r0.z + r0.w * r0.w
             + r1.x * r1.x + r1.y * r1.y + r1.z * r1.z + r1.w * r1.w;

#pragma unroll
    for (int off = 32; off > 0; off >>= 1) {
        s  += __shfl_down(s,  off);
        ss += __shfl_down(ss, off);
    }
    __shared__ float sh_s[4], sh_ss[4];
    const int lane = tid & 63;
    const int wave = tid >> 6;
    if (lane == 0) { sh_s[wave] = s; sh_ss[wave] = ss; }
    __syncthreads();
    if (tid == 0) {
        pr [bid] = sh_s [0] + sh_s [1] + sh_s [2] + sh_s [3];
        pr2[bid] = sh_ss[0] + sh_ss[1] + sh_ss[2] + sh_ss[3];
    }
}

// ---------------------------------------------------------------------------
// Kernel B: 7x7 local unbiased variance over the (L3-warm) residual.
// 64x32 tile + reflect halo in LDS; ring-buffer row-sum slide, 8 px/thread;
// per-block partial sum of pix_var*r -> pc. No atomics.
// ---------------------------------------------------------------------------
__global__ __launch_bounds__(TPB) void k_lvar(const float* __restrict__ resid,
                                              float* __restrict__ pc) {
    __shared__ __align__(16) float tile[TILE_H * TSTRIDE];

    const int bid = blockIdx.x;
    const int n   = bid >> 7;              // 128 tiles per image
    const int t   = bid & 127;
    const int by  = t >> 3;                // 0..15
    const int bx  = t & 7;                 // 0..7
    const int tid = threadIdx.x;
    const int y0  = by * TSY - PAD;

    const float*  rb = resid + (size_t)n * HW;
    const float4* R4 = (const float4*)rb;

    // interior: 38 rows x 16 float4 = 608 slots = 2*256 + 96
#pragma unroll
    for (int it = 0; it < 3; ++it) {
        const int s = tid + it * TPB;
        if (it < 2 || tid < 96) {
            const int row = s >> 4;
            const int c4  = s & 15;
            const int gy  = reflect_i(y0 + row, H_DIM);
            const float4 v = R4[gy * (W_DIM / 4) + bx * 16 + c4];
            *(float4*)&tile[row * TSTRIDE + 4 + c4 * 4] = v;   // 16B-aligned
        }
    }
    // halo: 38 rows x (3 left + 3 right) = 228 slots
    if (tid < TILE_H * 6) {
        const int row = tid / 6;
        const int k   = tid - row * 6;
        const int lx  = (k < 3) ? (1 + k) : (65 + k);          // 1..3 or 68..70
        const int gx  = reflect_i(bx * TSX + lx - 4, W_DIM);
        const int gy  = reflect_i(y0 + row, H_DIM);
        tile[row * TSTRIDE + lx] = rb[gy * W_DIM + gx];
    }
    __syncthreads();

    // 8 vertically-adjacent output pixels per thread (ring of row sums)
    const int tx = tid & 63;               // output column 0..63
    const int r0 = (tid >> 6) << 3;        // output rows r0..r0+7

    float rS[KS], rSS[KS];
    float S = 0.f, SS = 0.f;
#pragma unroll
    for (int d = 0; d < KS; ++d) {
        const float* rw = &tile[(r0 + d) * TSTRIDE + 1 + tx];
        float s = 0.f, ss = 0.f;
#pragma unroll
        for (int j = 0; j < KS; ++j) { const float v = rw[j]; s += v; ss += v * v; }
        rS[d] = s; rSS[d] = ss; S += s; SS += ss;
    }

    float acc_c = 0.f;
#pragma unroll
    for (int k = 0; k < 8; ++k) {
        if (k > 0) {
            const float* rw = &tile[(r0 + 6 + k) * TSTRIDE + 1 + tx];
            float s = 0.f, ss = 0.f;
#pragma unroll
            for (int j = 0; j < KS; ++j) { const float v = rw[j]; s += v; ss += v * v; }
            S  += s  - rS[k - 1];          // exactly 7 slides: slots 0..6, no reuse
            SS += ss - rSS[k - 1];
        }
        const float pix_var = (SS - S * S * (1.0f / 49.0f)) * (1.0f / 48.0f);
        const float center  = tile[(r0 + k + 3) * TSTRIDE + 4 + tx];
        acc_c += pix_var * center;
    }

#pragma unroll
    for (int off = 32; off > 0; off >>= 1)
        acc_c += __shfl_down(acc_c, off);

    __shared__ float sh_c[4];
    const int lane = tid & 63;
    const int wave = tid >> 6;
    if (lane == 0) sh_c[wave] = acc_c;
    __syncthreads();
    if (tid == 0)
        pc[bid] = sh_c[0] + sh_c[1] + sh_c[2] + sh_c[3];
}

// ---------------------------------------------------------------------------
// Kernel C: wave w reduces image w's partials in double; applies pvar^0.2;
// thread 0 writes the scalar.
// ---------------------------------------------------------------------------
__global__ void k_final(const float* __restrict__ pr,
                        const float* __restrict__ pr2,
                        const float* __restrict__ pc,
                        float* __restrict__ out) {
    __shared__ double sh[N_IMG];
    const int tid  = threadIdx.x;       // 1024 threads = 16 waves
    const int w    = tid >> 6;          // image index
    const int lane = tid & 63;

    double R = 0.0, R2 = 0.0, Cs = 0.0;
    for (int i = lane; i < A_PER_IMG; i += 64) {
        R  += (double)pr [w * A_PER_IMG + i];
        R2 += (double)pr2[w * A_PER_IMG + i];
    }
    for (int i = lane; i < TILES_PER_IMG; i += 64)
        Cs += (double)pc[w * TILES_PER_IMG + i];

#pragma unroll
    for (int off = 32; off > 0; off >>= 1) {
        R  += __shfl_down(R,  off);
        R2 += __shfl_down(R2, off);
        Cs += __shfl_down(Cs, off);
    }
    if (lane == 0) {
        const double pvar = (R2 - R * R / (double)HW) / (double)(HW - 1);
        sh[w] = pow(pvar, 0.2) * Cs;
    }
    __syncthreads();
    if (tid == 0) {
        double s = 0.0;
        for (int i = 0; i < N_IMG; ++i) s += sh[i];
        out[0] = (float)(s / ((double)N_IMG * C_CH * HW));
    }
}

extern "C" void kernel_launch(void* const* d_in, const int* in_sizes, int n_in,
                              void* d_out, int out_size, void* d_ws, size_t ws_size,
                              hipStream_t stream) {
    const float4* pred = (const float4*)d_in[0];
    const float4* targ = (const float4*)d_in[1];

    float4* resid = (float4*)d_ws;                       // 16 MB
    float*  pr    = (float*)((char*)d_ws + (size_t)N_IMG * HW * sizeof(float));
    float*  pr2   = pr  + ABLOCKS;
    float*  pc    = pr2 + ABLOCKS;
    float*  out   = (float*)d_out;

    k_resid<<<ABLOCKS, TPB, 0, stream>>>(pred, targ, resid, pr, pr2);
    k_lvar <<<BBLOCKS, TPB, 0, stream>>>((const float*)resid, pc);
    k_final<<<1, 1024, 0, stream>>>(pr, pr2, pc, out);
}

// Round 7
// 127.519 us; speedup vs baseline: 1.7668x; 1.0207x over previous
//
#include <hip/hip_runtime.h>
#include <math.h>

// Problem constants
#define N_IMG 16
#define C_CH 3
#define H_DIM 512
#define W_DIM 512
#define HW (H_DIM * W_DIM)              // 262144
#define HW4 (HW / 4)                    // 65536 float4 per plane
#define KS 7
#define PAD 3

// Tiling: 64 wide x 32 tall output tile, 3-halo each side.
#define TSX 64
#define TSY 32
#define TILE_H (TSY + 2 * PAD)          // 38
#define TSTRIDE 72                      // LDS row stride; interior cols [4..67], halo [1..3],[68..70]
#define TPB 256
#define TPT 2                           // tiles per block (double-buffer pipeline depth)
#define TILES_PER_IMG 128               // (512/64)*(512/32)
#define NTILES (N_IMG * TILES_PER_IMG)  // 2048
#define NBLOCKS (NTILES / TPT)          // 1024
#define BLK_PER_IMG (NBLOCKS / N_IMG)   // 64

__device__ __forceinline__ int reflect_i(int g, int n) {
    // jnp 'reflect' (no edge duplication)
    return (g < 0) ? -g : ((g >= n) ? (2 * n - 2 - g) : g);
}

// Raw per-thread tile data held in registers while the previous tile's
// stencil runs (this is what keeps ~18 16B loads in flight per lane).
struct TileRegs {
    float4 pv[3][3], qv[3][3];   // [slot][channel]
    float  hp[3], hq[3];         // halo scalars
};

__device__ __forceinline__ void load_tile(int tile, int tid,
                                          const float4* __restrict__ pred4,
                                          const float4* __restrict__ targ4,
                                          const float* __restrict__ predf,
                                          const float* __restrict__ targf,
                                          TileRegs& R) {
    const int n  = tile >> 7;            // 128 tiles per image
    const int t  = tile & 127;
    const int by = t >> 3;               // 0..15
    const int bx = t & 7;                // 0..7
    const int y0 = by * TSY - PAD;
    const int b4 = n * C_CH * HW4;

    // interior: 38 rows x 16 float4 = 608 slots = 2*256 + 96
#pragma unroll
    for (int it = 0; it < 3; ++it) {
        const int s = tid + it * TPB;
        if (it < 2 || tid < 96) {
            const int row = s >> 4;
            const int c4  = s & 15;
            const int gy  = reflect_i(y0 + row, H_DIM);
            const int off = b4 + gy * (W_DIM / 4) + bx * 16 + c4;
            R.pv[it][0] = pred4[off];
            R.pv[it][1] = pred4[off + HW4];
            R.pv[it][2] = pred4[off + 2 * HW4];
            R.qv[it][0] = targ4[off];
            R.qv[it][1] = targ4[off + HW4];
            R.qv[it][2] = targ4[off + 2 * HW4];
        }
    }
    // halo: 38 rows x (3 left + 3 right) = 228 slots
    if (tid < TILE_H * 6) {
        const int row = tid / 6;
        const int k   = tid - row * 6;
        const int lx  = (k < 3) ? (1 + k) : (65 + k);          // 1..3 or 68..70
        const int gx  = reflect_i(bx * TSX + lx - 4, W_DIM);
        const int gy  = reflect_i(y0 + row, H_DIM);
        const int off = n * C_CH * HW + gy * W_DIM + gx;
#pragma unroll
        for (int c = 0; c < 3; ++c) { R.hp[c] = predf[off + c * HW]; R.hq[c] = targf[off + c * HW]; }
    }
}

__device__ __forceinline__ void store_tile(float* __restrict__ buf, int tid,
                                           const TileRegs& R) {
    // consume the registers: residual -> LDS (this is where vmcnt waits land)
#pragma unroll
    for (int it = 0; it < 3; ++it) {
        const int s = tid + it * TPB;
        if (it < 2 || tid < 96) {
            const int row = s >> 4;
            const int c4  = s & 15;
            float4 r;
            r.x = fabsf(R.qv[it][0].x - R.pv[it][0].x) + fabsf(R.qv[it][1].x - R.pv[it][1].x) + fabsf(R.qv[it][2].x - R.pv[it][2].x);
            r.y = fabsf(R.qv[it][0].y - R.pv[it][0].y) + fabsf(R.qv[it][1].y - R.pv[it][1].y) + fabsf(R.qv[it][2].y - R.pv[it][2].y);
            r.z = fabsf(R.qv[it][0].z - R.pv[it][0].z) + fabsf(R.qv[it][1].z - R.pv[it][1].z) + fabsf(R.qv[it][2].z - R.pv[it][2].z);
            r.w = fabsf(R.qv[it][0].w - R.pv[it][0].w) + fabsf(R.qv[it][1].w - R.pv[it][1].w) + fabsf(R.qv[it][2].w - R.pv[it][2].w);
            *(float4*)&buf[row * TSTRIDE + 4 + c4 * 4] = r;    // 16B-aligned
        }
    }
    if (tid < TILE_H * 6) {
        const int row = tid / 6;
        const int k   = tid - row * 6;
        const int lx  = (k < 3) ? (1 + k) : (65 + k);
        buf[row * TSTRIDE + lx] = fabsf(R.hq[0] - R.hp[0])
                                + fabsf(R.hq[1] - R.hp[1])
                                + fabsf(R.hq[2] - R.hp[2]);
    }
}

__device__ __forceinline__ void stencil(const float* __restrict__ buf, int tid,
                                        float& acc_r, float& acc_r2, float& acc_c) {
    // 8 vertically-adjacent output pixels per thread, ring-buffer row sums.
    const int tx = tid & 63;               // output column 0..63
    const int r0 = (tid >> 6) << 3;        // output rows r0..r0+7

    float rS[KS], rSS[KS];
    float S = 0.f, SS = 0.f;
#pragma unroll
    for (int d = 0; d < KS; ++d) {
        const float* rw = &buf[(r0 + d) * TSTRIDE + 1 + tx];
        float s = 0.f, ss = 0.f;
#pragma unroll
        for (int j = 0; j < KS; ++j) { const float v = rw[j]; s += v; ss += v * v; }
        rS[d] = s; rSS[d] = ss; S += s; SS += ss;
    }
#pragma unroll
    for (int k = 0; k < 8; ++k) {
        if (k > 0) {
            const float* rw = &buf[(r0 + 6 + k) * TSTRIDE + 1 + tx];
            float s = 0.f, ss = 0.f;
#pragma unroll
            for (int j = 0; j < KS; ++j) { const float v = rw[j]; s += v; ss += v * v; }
            S  += s  - rS[k - 1];          // exactly 7 slides: slots 0..6, no reuse
            SS += ss - rSS[k - 1];
        }
        const float pix_var = (SS - S * S * (1.0f / 49.0f)) * (1.0f / 48.0f);
        const float center  = buf[(r0 + k + 3) * TSTRIDE + 4 + tx];
        acc_r  += center;
        acc_r2 += center * center;
        acc_c  += pix_var * center;
    }
}

// ---------------------------------------------------------------------------
// Pipelined fused kernel: per block, TPT tiles with double-buffered LDS.
// store(t) -> bar -> issue loads(t+1) -> stencil(t): tile t+1's HBM latency
// hides under tile t's stencil. No fences, no atomics.
// ---------------------------------------------------------------------------
__global__ __launch_bounds__(TPB) void k_fused(const float4* __restrict__ pred4,
                                               const float4* __restrict__ targ4,
                                               const float* __restrict__ predf,
                                               const float* __restrict__ targf,
                                               float* __restrict__ pr,
                                               float* __restrict__ pr2,
                                               float* __restrict__ pc) {
    __shared__ __align__(16) float buf[2][TILE_H * TSTRIDE];

    const int bid = blockIdx.x;
    const int tid = threadIdx.x;
    const int tb0 = bid * TPT;             // both tiles land in the same image (TPT | 128)

    TileRegs R;
    load_tile(tb0, tid, pred4, targ4, predf, targf, R);

    float acc_r = 0.f, acc_r2 = 0.f, acc_c = 0.f;
#pragma unroll
    for (int t = 0; t < TPT; ++t) {
        store_tile(buf[t & 1], tid, R);
        __syncthreads();
        if (t + 1 < TPT)
            load_tile(tb0 + t + 1, tid, pred4, targ4, predf, targf, R);
        stencil(buf[t & 1], tid, acc_r, acc_r2, acc_c);
    }

    // block reduce 3 floats -> per-block partials
#pragma unroll
    for (int off = 32; off > 0; off >>= 1) {
        acc_r  += __shfl_down(acc_r,  off);
        acc_r2 += __shfl_down(acc_r2, off);
        acc_c  += __shfl_down(acc_c,  off);
    }
    __shared__ float sh_r[4], sh_r2[4], sh_c[4];
    const int lane = tid & 63;
    const int wave = tid >> 6;
    if (lane == 0) { sh_r[wave] = acc_r; sh_r2[wave] = acc_r2; sh_c[wave] = acc_c; }
    __syncthreads();
    if (tid == 0) {
        pr [bid] = sh_r [0] + sh_r [1] + sh_r [2] + sh_r [3];
        pr2[bid] = sh_r2[0] + sh_r2[1] + sh_r2[2] + sh_r2[3];
        pc [bid] = sh_c [0] + sh_c [1] + sh_c [2] + sh_c [3];
    }
}

// ---------------------------------------------------------------------------
// Finalize: wave w reduces image w's 64 block partials in double; applies
// patch_w = pvar^0.2; thread 0 writes the scalar.
// ---------------------------------------------------------------------------
__global__ void k_final(const float* __restrict__ pr,
                        const float* __restrict__ pr2,
                        const float* __restrict__ pc,
                        float* __restrict__ out) {
    __shared__ double sh[N_IMG];
    const int tid  = threadIdx.x;       // 1024 threads = 16 waves
    const int w    = tid >> 6;          // image index
    const int lane = tid & 63;

    double R = 0.0, R2 = 0.0, Cs = 0.0;
    if (lane < BLK_PER_IMG) {
        const int idx = w * BLK_PER_IMG + lane;
        R  = (double)pr[idx];
        R2 = (double)pr2[idx];
        Cs = (double)pc[idx];
    }
#pragma unroll
    for (int off = 32; off > 0; off >>= 1) {
        R  += __shfl_down(R,  off);
        R2 += __shfl_down(R2, off);
        Cs += __shfl_down(Cs, off);
    }
    if (lane == 0) {
        const double pvar = (R2 - R * R / (double)HW) / (double)(HW - 1);
        sh[w] = pow(pvar, 0.2) * Cs;
    }
    __syncthreads();
    if (tid == 0) {
        double s = 0.0;
        for (int i = 0; i < N_IMG; ++i) s += sh[i];
        out[0] = (float)(s / ((double)N_IMG * C_CH * HW));
    }
}

extern "C" void kernel_launch(void* const* d_in, const int* in_sizes, int n_in,
                              void* d_out, int out_size, void* d_ws, size_t ws_size,
                              hipStream_t stream) {
    const float* predf = (const float*)d_in[0];
    const float* targf = (const float*)d_in[1];

    float* pr  = (float*)d_ws;
    float* pr2 = pr  + NBLOCKS;
    float* pc  = pr2 + NBLOCKS;
    float* out = (float*)d_out;

    k_fused<<<NBLOCKS, TPB, 0, stream>>>((const float4*)predf, (const float4*)targf,
                                         predf, targf, pr, pr2, pc);
    k_final<<<1, 1024, 0, stream>>>(pr, pr2, pc, out);
}